// Round 2
// baseline (2637.642 us; speedup 1.0000x reference)
//
#include <hip/hip_runtime.h>

#define N_USERS 200000
#define N_ITEMS 400000
#define N_NODES 600000   // N_USERS + N_ITEMS
#define EMB_DIM 128
#define N_EDGES 3000000

#define SCAN_CHUNK 4096
#define N_CHUNKS ((N_NODES + SCAN_CHUNK - 1) / SCAN_CHUNK)   // 147

typedef float __attribute__((ext_vector_type(2))) f32x2v;
typedef int   __attribute__((ext_vector_type(2))) i32x2v;

__device__ __forceinline__ void nt_store2(float* p, float a, float b) {
    f32x2v v; v.x = a; v.y = b;
    __builtin_nontemporal_store(v, (f32x2v*)p);
}
__device__ __forceinline__ f32x2v nt_load2(const float* p) {
    return __builtin_nontemporal_load((const f32x2v*)p);
}

// ---------------------------------------------------------------------------
// CSR build: zero counts -> histogram -> 3-phase exclusive scan -> bucket fill
// ---------------------------------------------------------------------------
__global__ void k_zero_i32(int* __restrict__ p, int n) {
    for (int i = blockIdx.x * blockDim.x + threadIdx.x; i < n;
         i += gridDim.x * blockDim.x)
        p[i] = 0;
}

__global__ void k_hist(const int* __restrict__ row, int* __restrict__ cnt) {
    for (int e = blockIdx.x * blockDim.x + threadIdx.x; e < N_EDGES;
         e += gridDim.x * blockDim.x)
        atomicAdd(&cnt[row[e]], 1);
}

__global__ void k_scan_part(const int* __restrict__ cnt, int* __restrict__ partial) {
    __shared__ int s[256];
    const int t = threadIdx.x;
    const int base = blockIdx.x * SCAN_CHUNK + t * 16;
    int sum = 0;
    #pragma unroll
    for (int k = 0; k < 16; ++k) {
        int i = base + k;
        if (i < N_NODES) sum += cnt[i];
    }
    s[t] = sum; __syncthreads();
    for (int off = 128; off > 0; off >>= 1) {
        if (t < off) s[t] += s[t + off];
        __syncthreads();
    }
    if (t == 0) partial[blockIdx.x] = s[0];
}

__global__ void k_scan_top(int* partial, int* rp) {
    if (threadIdx.x == 0 && blockIdx.x == 0) {
        int run = 0;
        for (int i = 0; i < N_CHUNKS; ++i) {
            int v = partial[i];
            partial[i] = run;
            run += v;
        }
        rp[N_NODES] = run;   // == N_EDGES
    }
}

// cnt_in and cursor alias (same buffer) — each index read/written by exactly
// one thread, all reads complete before writes. No __restrict__ on purpose.
__global__ void k_scan_apply(const int* cnt_in, const int* __restrict__ partial,
                             int* __restrict__ rp, int* cursor) {
    __shared__ int s[256];
    const int t = threadIdx.x;
    const int base = blockIdx.x * SCAN_CHUNK + t * 16;
    int c[16];
    int tsum = 0;
    #pragma unroll
    for (int k = 0; k < 16; ++k) {
        int i = base + k;
        c[k] = (i < N_NODES) ? cnt_in[i] : 0;
        tsum += c[k];
    }
    s[t] = tsum; __syncthreads();
    for (int off = 1; off < 256; off <<= 1) {
        int v = (t >= off) ? s[t - off] : 0;
        __syncthreads();
        s[t] += v;
        __syncthreads();
    }
    int pre = partial[blockIdx.x] + s[t] - tsum;   // exclusive prefix
    #pragma unroll
    for (int k = 0; k < 16; ++k) {
        int i = base + k;
        if (i < N_NODES) { rp[i] = pre; cursor[i] = pre; }
        pre += c[k];
    }
}

__global__ void k_fill(const int* __restrict__ row, const int* __restrict__ col,
                       const float* __restrict__ val, int* cursor,
                       int2* __restrict__ ev) {
    for (int e = blockIdx.x * blockDim.x + threadIdx.x; e < N_EDGES;
         e += gridDim.x * blockDim.x) {
        int r = row[e];
        int p = atomicAdd(&cursor[r], 1);
        ev[p] = make_int2(col[e], __float_as_int(val[e]));
    }
}

// ---------------------------------------------------------------------------
// Pull-mode CSR SpMM over ONE dim-half (h = 0: dims 0-63, h = 1: dims 64-127).
// 32 lanes per row, float2 per lane. Gather loads cached; everything streamed
// (ev, y-store, epilogue reads) is non-temporal so the 153.6 MB gather slab
// stays L3-resident.
// ---------------------------------------------------------------------------

// layer 1: y1[r] = sum val * x0[col], x0 = concat(eu, ei) read in place
__global__ void k_spmm_l1(const int* __restrict__ rp, const int2* __restrict__ ev,
                          const float* __restrict__ eu, const float* __restrict__ ei,
                          float* __restrict__ y1, int h) {
    const int lane = threadIdx.x & 31;
    const int grp  = threadIdx.x >> 5;
    const int rpb  = blockDim.x >> 5;          // 8 rows per block
    const int foff = ((h << 5) + lane) << 1;   // float offset within row
    for (int r = blockIdx.x * rpb + grp; r < N_NODES; r += gridDim.x * rpb) {
        const int beg = rp[r], end = rp[r + 1];
        float sx = 0.f, sy = 0.f;
        for (int i = beg; i < end; ++i) {
            i32x2v e = __builtin_nontemporal_load((const i32x2v*)(ev + i));
            const float v = __int_as_float(e.y);
            const int   c = e.x;
            const float* src = (c < N_USERS)
                ? (eu + ((size_t)c << 7))
                : (ei + ((size_t)(c - N_USERS) << 7));
            f32x2v xv = *(const f32x2v*)(src + foff);
            sx += v * xv.x; sy += v * xv.y;
        }
        nt_store2(y1 + ((size_t)r << 7) + foff, sx, sy);
    }
}

// layer 2: y2[r] = sum val * y1[col]
__global__ void k_spmm_mid(const int* __restrict__ rp, const int2* __restrict__ ev,
                           const float* __restrict__ x, float* __restrict__ y, int h) {
    const int lane = threadIdx.x & 31;
    const int grp  = threadIdx.x >> 5;
    const int rpb  = blockDim.x >> 5;
    const int foff = ((h << 5) + lane) << 1;
    for (int r = blockIdx.x * rpb + grp; r < N_NODES; r += gridDim.x * rpb) {
        const int beg = rp[r], end = rp[r + 1];
        float sx = 0.f, sy = 0.f;
        for (int i = beg; i < end; ++i) {
            i32x2v e = __builtin_nontemporal_load((const i32x2v*)(ev + i));
            const float v = __int_as_float(e.y);
            f32x2v xv = *(const f32x2v*)(x + ((size_t)e.x << 7) + foff);
            sx += v * xv.x; sy += v * xv.y;
        }
        nt_store2(y + ((size_t)r << 7) + foff, sx, sy);
    }
}

// layer 3 + deferred mean: out[r] = 0.25*(x0[r] + y1[r] + y2[r] + A·y2[r])
__global__ void k_spmm_l3(const int* __restrict__ rp, const int2* __restrict__ ev,
                          const float* __restrict__ y2, const float* __restrict__ eu,
                          const float* __restrict__ ei, const float* __restrict__ y1,
                          float* __restrict__ out, int h) {
    const int lane = threadIdx.x & 31;
    const int grp  = threadIdx.x >> 5;
    const int rpb  = blockDim.x >> 5;
    const int foff = ((h << 5) + lane) << 1;
    for (int r = blockIdx.x * rpb + grp; r < N_NODES; r += gridDim.x * rpb) {
        const int beg = rp[r], end = rp[r + 1];
        float sx = 0.f, sy = 0.f;
        for (int i = beg; i < end; ++i) {
            i32x2v e = __builtin_nontemporal_load((const i32x2v*)(ev + i));
            const float v = __int_as_float(e.y);
            f32x2v xv = *(const f32x2v*)(y2 + ((size_t)e.x << 7) + foff);
            sx += v * xv.x; sy += v * xv.y;
        }
        const size_t o = ((size_t)r << 7) + foff;
        const float* x0p = (r < N_USERS) ? (eu + o)
                                         : (ei + o - ((size_t)N_USERS << 7));
        f32x2v x0 = nt_load2(x0p);
        f32x2v a1 = nt_load2(y1 + o);
        f32x2v a2 = nt_load2(y2 + o);
        nt_store2(out + o,
                  0.25f * ((x0.x + a1.x) + (a2.x + sx)),
                  0.25f * ((x0.y + a1.y) + (a2.y + sy)));
    }
}

extern "C" void kernel_launch(void* const* d_in, const int* in_sizes, int n_in,
                              void* d_out, int out_size, void* d_ws, size_t ws_size,
                              hipStream_t stream) {
    const float* eu   = (const float*)d_in[0];
    const float* ei   = (const float*)d_in[1];
    const int*   erow = (const int*)d_in[2];
    const int*   ecol = (const int*)d_in[3];
    const float* eval = (const float*)d_in[4];

    float* out = (float*)d_out;

    // workspace layout (same footprint as the proven round-1 layout)
    const size_t nodef = (size_t)N_NODES * EMB_DIM;
    char* p = (char*)d_ws;
    float* ws0  = (float*)p; p += nodef * sizeof(float);          // y1
    float* ws1  = (float*)p; p += nodef * sizeof(float);          // y2
    int2*  ev   = (int2*)p;  p += (size_t)N_EDGES * sizeof(int2); // packed (col,val)
    int*   rp   = (int*)p;   p += ((size_t)N_NODES + 1) * sizeof(int);
    int*   cnt  = (int*)p;   p += (size_t)N_NODES * sizeof(int);  // counts / cursor
    int*   part = (int*)p;   p += 256 * sizeof(int);              // chunk partials

    const int EG = (N_EDGES + 255) / 256;   // 11,719
    const int SG = (N_NODES + 7) / 8;       // 75,000  (8 rows x 256 thr)

    // ---- build CSR (edge list identical for all 3 layers) ----
    k_zero_i32<<<1024, 256, 0, stream>>>(cnt, N_NODES);
    k_hist<<<EG, 256, 0, stream>>>(erow, cnt);
    k_scan_part<<<N_CHUNKS, 256, 0, stream>>>(cnt, part);
    k_scan_top<<<1, 1, 0, stream>>>(part, rp);
    k_scan_apply<<<N_CHUNKS, 256, 0, stream>>>(cnt, part, rp, cnt);
    k_fill<<<EG, 256, 0, stream>>>(erow, ecol, eval, cnt, ev);

    // ---- 3 layers, each split into two L3-resident dim-half passes ----
    k_spmm_l1 <<<SG, 256, 0, stream>>>(rp, ev, eu, ei, ws0, 0);
    k_spmm_l1 <<<SG, 256, 0, stream>>>(rp, ev, eu, ei, ws0, 1);

    k_spmm_mid<<<SG, 256, 0, stream>>>(rp, ev, ws0, ws1, 0);
    k_spmm_mid<<<SG, 256, 0, stream>>>(rp, ev, ws0, ws1, 1);

    k_spmm_l3 <<<SG, 256, 0, stream>>>(rp, ev, ws1, eu, ei, ws0, out, 0);
    k_spmm_l3 <<<SG, 256, 0, stream>>>(rp, ev, ws1, eu, ei, ws0, out, 1);
}

// Round 3
// 1720.381 us; speedup vs baseline: 1.5332x; 1.5332x over previous
//
#include <hip/hip_runtime.h>

#define N_USERS 200000
#define N_ITEMS 400000
#define N_NODES 600000   // N_USERS + N_ITEMS
#define EMB_DIM 128
#define N_EDGES 3000000

#define SCAN_CHUNK 4096
#define N_CHUNKS ((N_NODES + SCAN_CHUNK - 1) / SCAN_CHUNK)   // 147

typedef float __attribute__((ext_vector_type(2))) f32x2v;

__device__ __forceinline__ void nt_store2(float* p, float a, float b) {
    f32x2v v; v.x = a; v.y = b;
    __builtin_nontemporal_store(v, (f32x2v*)p);
}
__device__ __forceinline__ f32x2v nt_load2(const float* p) {
    return __builtin_nontemporal_load((const f32x2v*)p);
}

// ---------------------------------------------------------------------------
// CSR build: zero counts -> histogram -> 3-phase exclusive scan -> bucket fill
// ---------------------------------------------------------------------------
__global__ void k_zero_i32(int* __restrict__ p, int n) {
    for (int i = blockIdx.x * blockDim.x + threadIdx.x; i < n;
         i += gridDim.x * blockDim.x)
        p[i] = 0;
}

__global__ void k_hist(const int* __restrict__ row, int* __restrict__ cnt) {
    for (int e = blockIdx.x * blockDim.x + threadIdx.x; e < N_EDGES;
         e += gridDim.x * blockDim.x)
        atomicAdd(&cnt[row[e]], 1);
}

__global__ void k_scan_part(const int* __restrict__ cnt, int* __restrict__ partial) {
    __shared__ int s[256];
    const int t = threadIdx.x;
    const int base = blockIdx.x * SCAN_CHUNK + t * 16;
    int sum = 0;
    #pragma unroll
    for (int k = 0; k < 16; ++k) {
        int i = base + k;
        if (i < N_NODES) sum += cnt[i];
    }
    s[t] = sum; __syncthreads();
    for (int off = 128; off > 0; off >>= 1) {
        if (t < off) s[t] += s[t + off];
        __syncthreads();
    }
    if (t == 0) partial[blockIdx.x] = s[0];
}

__global__ void k_scan_top(int* partial, int* rp) {
    if (threadIdx.x == 0 && blockIdx.x == 0) {
        int run = 0;
        for (int i = 0; i < N_CHUNKS; ++i) {
            int v = partial[i];
            partial[i] = run;
            run += v;
        }
        rp[N_NODES] = run;   // == N_EDGES
    }
}

// cnt_in and cursor alias (same buffer) — each index read/written by exactly
// one thread, all reads complete before writes. No __restrict__ on purpose.
__global__ void k_scan_apply(const int* cnt_in, const int* __restrict__ partial,
                             int* __restrict__ rp, int* cursor) {
    __shared__ int s[256];
    const int t = threadIdx.x;
    const int base = blockIdx.x * SCAN_CHUNK + t * 16;
    int c[16];
    int tsum = 0;
    #pragma unroll
    for (int k = 0; k < 16; ++k) {
        int i = base + k;
        c[k] = (i < N_NODES) ? cnt_in[i] : 0;
        tsum += c[k];
    }
    s[t] = tsum; __syncthreads();
    for (int off = 1; off < 256; off <<= 1) {
        int v = (t >= off) ? s[t - off] : 0;
        __syncthreads();
        s[t] += v;
        __syncthreads();
    }
    int pre = partial[blockIdx.x] + s[t] - tsum;   // exclusive prefix
    #pragma unroll
    for (int k = 0; k < 16; ++k) {
        int i = base + k;
        if (i < N_NODES) { rp[i] = pre; cursor[i] = pre; }
        pre += c[k];
    }
}

__global__ void k_fill(const int* __restrict__ row, const int* __restrict__ col,
                       const float* __restrict__ val, int* cursor,
                       int2* __restrict__ ev) {
    for (int e = blockIdx.x * blockDim.x + threadIdx.x; e < N_EDGES;
         e += gridDim.x * blockDim.x) {
        int r = row[e];
        int p = atomicAdd(&cursor[r], 1);
        ev[p] = make_int2(col[e], __float_as_int(val[e]));
    }
}

// ---------------------------------------------------------------------------
// Pull-mode CSR SpMM, one 64-lane wave per row, float2 per lane (full 128 dims).
// Edge metadata is loaded cooperatively (one coalesced burst of up to 64
// (col,val) pairs into per-lane registers), then broadcast with v_readlane so
// col/val land in SGPRs. Edge loop unrolled x4 so 4 independent x-row gathers
// are in flight per wave — attacks the serial ev->x latency chain.
// ---------------------------------------------------------------------------
__device__ __forceinline__ const float* xrow_split(const float* eu, const float* ei,
                                                   int c) {
    return (c < N_USERS) ? eu + ((size_t)c << 7)
                         : ei + (((size_t)(c - N_USERS)) << 7);
}

template <int SPLIT>
__device__ __forceinline__ f32x2v row_gather(const int* __restrict__ rp,
                                             const int2* __restrict__ ev,
                                             const float* __restrict__ x,
                                             const float* __restrict__ eu,
                                             const float* __restrict__ ei,
                                             int r, int lane) {
    const int beg = rp[r];
    const int end = rp[r + 1];
    const int foff = lane << 1;
    float sx = 0.f, sy = 0.f;
    for (int base = beg; base < end; base += 64) {
        const int n = (end - base < 64) ? (end - base) : 64;
        int2 my = make_int2(0, 0);
        if (lane < n) my = ev[base + lane];
        int j = 0;
        for (; j + 4 <= n; j += 4) {
            const int c0 = __builtin_amdgcn_readlane(my.x, j + 0);
            const int c1 = __builtin_amdgcn_readlane(my.x, j + 1);
            const int c2 = __builtin_amdgcn_readlane(my.x, j + 2);
            const int c3 = __builtin_amdgcn_readlane(my.x, j + 3);
            const float v0 = __int_as_float(__builtin_amdgcn_readlane(my.y, j + 0));
            const float v1 = __int_as_float(__builtin_amdgcn_readlane(my.y, j + 1));
            const float v2 = __int_as_float(__builtin_amdgcn_readlane(my.y, j + 2));
            const float v3 = __int_as_float(__builtin_amdgcn_readlane(my.y, j + 3));
            const float* p0 = SPLIT ? xrow_split(eu, ei, c0) : x + ((size_t)c0 << 7);
            const float* p1 = SPLIT ? xrow_split(eu, ei, c1) : x + ((size_t)c1 << 7);
            const float* p2 = SPLIT ? xrow_split(eu, ei, c2) : x + ((size_t)c2 << 7);
            const float* p3 = SPLIT ? xrow_split(eu, ei, c3) : x + ((size_t)c3 << 7);
            const f32x2v x0 = *(const f32x2v*)(p0 + foff);
            const f32x2v x1 = *(const f32x2v*)(p1 + foff);
            const f32x2v x2 = *(const f32x2v*)(p2 + foff);
            const f32x2v x3 = *(const f32x2v*)(p3 + foff);
            sx += v0 * x0.x; sy += v0 * x0.y;
            sx += v1 * x1.x; sy += v1 * x1.y;
            sx += v2 * x2.x; sy += v2 * x2.y;
            sx += v3 * x3.x; sy += v3 * x3.y;
        }
        for (; j < n; ++j) {
            const int   c = __builtin_amdgcn_readlane(my.x, j);
            const float v = __int_as_float(__builtin_amdgcn_readlane(my.y, j));
            const float* p = SPLIT ? xrow_split(eu, ei, c) : x + ((size_t)c << 7);
            const f32x2v xv = *(const f32x2v*)(p + foff);
            sx += v * xv.x; sy += v * xv.y;
        }
    }
    f32x2v rv; rv.x = sx; rv.y = sy;
    return rv;
}

// layers 1 & 2: y[r] = sum val * x[col]   (SPLIT=1 reads concat(eu,ei) in place)
template <int SPLIT>
__global__ void __launch_bounds__(256)
k_spmm(const int* __restrict__ rp, const int2* __restrict__ ev,
       const float* __restrict__ x, const float* __restrict__ eu,
       const float* __restrict__ ei, float* __restrict__ y) {
    const int lane = threadIdx.x & 63;
    const int wv   = threadIdx.x >> 6;
    const int rpb  = blockDim.x >> 6;   // 4 rows per 256-block
    for (int r = blockIdx.x * rpb + wv; r < N_NODES; r += gridDim.x * rpb) {
        f32x2v a = row_gather<SPLIT>(rp, ev, x, eu, ei, r, lane);
        nt_store2(y + ((size_t)r << 7) + (lane << 1), a.x, a.y);
    }
}

// layer 3 + deferred mean: out[r] = 0.25*(x0[r] + y1[r] + y2[r] + A.y2[r])
__global__ void __launch_bounds__(256)
k_spmm_l3(const int* __restrict__ rp, const int2* __restrict__ ev,
          const float* __restrict__ y2, const float* __restrict__ eu,
          const float* __restrict__ ei, const float* __restrict__ y1,
          float* __restrict__ out) {
    const int lane = threadIdx.x & 63;
    const int wv   = threadIdx.x >> 6;
    const int rpb  = blockDim.x >> 6;
    for (int r = blockIdx.x * rpb + wv; r < N_NODES; r += gridDim.x * rpb) {
        f32x2v a = row_gather<0>(rp, ev, y2, nullptr, nullptr, r, lane);
        const size_t o = ((size_t)r << 7) + (lane << 1);
        const float* x0p = (r < N_USERS) ? (eu + o)
                                         : (ei + o - ((size_t)N_USERS << 7));
        const f32x2v x0 = nt_load2(x0p);                  // stream once
        const f32x2v a1 = nt_load2(y1 + o);               // stream once
        const f32x2v a2 = *(const f32x2v*)(y2 + o);       // likely cache-hit
        nt_store2(out + o,
                  0.25f * ((x0.x + a1.x) + (a2.x + a.x)),
                  0.25f * ((x0.y + a1.y) + (a2.y + a.y)));
    }
}

extern "C" void kernel_launch(void* const* d_in, const int* in_sizes, int n_in,
                              void* d_out, int out_size, void* d_ws, size_t ws_size,
                              hipStream_t stream) {
    const float* eu   = (const float*)d_in[0];
    const float* ei   = (const float*)d_in[1];
    const int*   erow = (const int*)d_in[2];
    const int*   ecol = (const int*)d_in[3];
    const float* eval = (const float*)d_in[4];

    float* out = (float*)d_out;

    // workspace layout (same footprint as the proven round-1 layout)
    const size_t nodef = (size_t)N_NODES * EMB_DIM;
    char* p = (char*)d_ws;
    float* ws0  = (float*)p; p += nodef * sizeof(float);          // y1
    float* ws1  = (float*)p; p += nodef * sizeof(float);          // y2
    int2*  ev   = (int2*)p;  p += (size_t)N_EDGES * sizeof(int2); // packed (col,val)
    int*   rp   = (int*)p;   p += ((size_t)N_NODES + 1) * sizeof(int);
    int*   cnt  = (int*)p;   p += (size_t)N_NODES * sizeof(int);  // counts / cursor
    int*   part = (int*)p;   p += 256 * sizeof(int);              // chunk partials

    const int EG = (N_EDGES + 255) / 256;   // 11,719
    const int SG = (N_NODES + 3) / 4;       // 150,000 (4 rows x 4 waves/block)

    // ---- build CSR (edge list identical for all 3 layers) ----
    k_zero_i32<<<1024, 256, 0, stream>>>(cnt, N_NODES);
    k_hist<<<EG, 256, 0, stream>>>(erow, cnt);
    k_scan_part<<<N_CHUNKS, 256, 0, stream>>>(cnt, part);
    k_scan_top<<<1, 1, 0, stream>>>(part, rp);
    k_scan_apply<<<N_CHUNKS, 256, 0, stream>>>(cnt, part, rp, cnt);
    k_fill<<<EG, 256, 0, stream>>>(erow, ecol, eval, cnt, ev);

    // ---- 3 layers, full-dim, epilogue fused into layer 3 ----
    k_spmm<1><<<SG, 256, 0, stream>>>(rp, ev, nullptr, eu, ei, ws0);  // y1
    k_spmm<0><<<SG, 256, 0, stream>>>(rp, ev, ws0, nullptr, nullptr, ws1);  // y2
    k_spmm_l3<<<SG, 256, 0, stream>>>(rp, ev, ws1, eu, ei, ws0, out);
}